// Round 3
// baseline (65.240 us; speedup 1.0000x reference)
//
#include <hip/hip_runtime.h>

typedef __attribute__((ext_vector_type(8)))  short   short8;
typedef __attribute__((ext_vector_type(4)))  unsigned uint4v;
typedef __attribute__((ext_vector_type(16))) float   f32x16;

constexpr int GRAM_BLOCKS = 384;
constexpr int MSE_BLOCKS  = 128;
constexpr int BLOCK       = 256;          // 4 waves
constexpr int SLAB_F      = 192;          // floats per (o,c) slab: 64 rows x 3
constexpr int CHUNK_F     = 3072;         // 16 slabs
constexpr int NCHUNK      = 16384;
constexpr int GRAM_WAVES  = GRAM_BLOCKS * 4;   // 1536 (chunk grid-stride)
constexpr int NSLICE      = 8;
constexpr unsigned MSE_N4 = 2097152u;          // 8388608 floats / 4
constexpr int MSE_THREADS = MSE_BLOCKS * BLOCK; // 32768 -> exactly 64 iters

// ws layout (floats):
//   [0 .. 128)                    msum per MSE block (plain stores, no init)
//   [128 .. 128 + 8*3072)         gram slices (atomicAdd, memset'd each call)
// slice entry encode: e = tile*1024 + reg*64 + lane ; tile 0 = G[0:32][0:32],
// 1 = G[0:32][32:64] (weighted x2 in finalize), 2 = G[32:64][32:64]

struct F3 { float v[3]; };                 // 12B -> global_load_dwordx3
struct Chunk { F3 a0[4], a1[4], b0[4], b1[4]; };

// pack two f32 -> one u32 of 2 bf16 (round-half-up): 2 add + 1 v_perm
__device__ __forceinline__ unsigned pk_bf16(float a, float b) {
  unsigned a2 = __builtin_bit_cast(unsigned, a) + 0x8000u;
  unsigned b2 = __builtin_bit_cast(unsigned, b) + 0x8000u;
  return __builtin_amdgcn_perm(b2, a2, 0x07060302u);
}

__device__ __forceinline__ void load_chunk(const float* __restrict__ W, int c,
                                           int laneoff, Chunk& ch) {
  const float* s = W + (size_t)c * CHUNK_F + laneoff;
#pragma unroll
  for (int bp = 0; bp < 4; ++bp) {
    const float* p = s + bp * 384;     // slab pair (2bp, 2bp+1) of this half
    ch.a0[bp] = *(const F3*)(p);       // slab even, row r
    ch.a1[bp] = *(const F3*)(p + 96);  // slab even, row r+32
    ch.b0[bp] = *(const F3*)(p + 192); // slab odd,  row r
    ch.b1[bp] = *(const F3*)(p + 288); // slab odd,  row r+32
  }
}

__device__ __forceinline__ void mac_chunk(const Chunk& c, f32x16& a00, f32x16& a01,
                                          f32x16& a11) {
#pragma unroll
  for (int k = 0; k < 3; ++k) {
    unsigned fl[4], fh[4];
#pragma unroll
    for (int bp = 0; bp < 4; ++bp) {
      fl[bp] = pk_bf16(c.a0[bp].v[k], c.b0[bp].v[k]);
      fh[bp] = pk_bf16(c.a1[bp].v[k], c.b1[bp].v[k]);
    }
    uint4v vl = {fl[0], fl[1], fl[2], fl[3]};
    uint4v vh = {fh[0], fh[1], fh[2], fh[3]};
    short8 lo = __builtin_bit_cast(short8, vl);
    short8 hv = __builtin_bit_cast(short8, vh);
    a00 = __builtin_amdgcn_mfma_f32_32x32x16_bf16(lo, lo, a00, 0, 0, 0);
    a01 = __builtin_amdgcn_mfma_f32_32x32x16_bf16(lo, hv, a01, 0, 0, 0);
    a11 = __builtin_amdgcn_mfma_f32_32x32x16_bf16(hv, hv, a11, 0, 0, 0);
  }
}

__global__ __launch_bounds__(BLOCK, 2) void k_main(
    const float* __restrict__ X, const float* __restrict__ Y,
    const float* __restrict__ W, float* __restrict__ ws) {
  __shared__ float red[2][3072];       // 24 KiB
  const int bid = blockIdx.x;
  const int tid = threadIdx.x;
  const int wave = tid >> 6;
  const int lane = tid & 63;

  if (bid >= GRAM_BLOCKS) {
    // ---------------- MSE partial (plain per-block store) ----------------
    const unsigned t0 = (unsigned)((bid - GRAM_BLOCKS) * BLOCK + tid);
    const float4* x4 = (const float4*)X;
    const float4* y4 = (const float4*)Y;
    float acc = 0.f;
#pragma unroll 8
    for (int it = 0; it < 64; ++it) {
      unsigned i = t0 + (unsigned)it * (unsigned)MSE_THREADS;
      float4 a = x4[i], b = y4[i];
      float d0 = a.x - b.x, d1 = a.y - b.y, d2 = a.z - b.z, d3 = a.w - b.w;
      acc += d0 * d0 + d1 * d1 + d2 * d2 + d3 * d3;
    }
#pragma unroll
    for (int o = 32; o; o >>= 1) acc += __shfl_xor(acc, o, 64);
    __shared__ float wsum[4];
    if (lane == 0) wsum[wave] = acc;
    __syncthreads();
    if (tid == 0) ws[bid - GRAM_BLOCKS] = wsum[0] + wsum[1] + wsum[2] + wsum[3];
    return;
  }

  // ------------- Gram partial: grid-stride chunks, reg double-buffer -------------
  const int r    = lane & 31;
  const int hi   = lane >> 5;
  const int laneoff = hi * 1536 + 3 * r;   // (hi*8 slabs)*192 + row r
  const int wg = bid * 4 + wave;           // 0..1535

  f32x16 a00{}, a01{}, a11{};
  Chunk ca, cb;
  int c = wg;
  load_chunk(W, c, laneoff, ca);
  c += GRAM_WAVES;
  for (;;) {
    if (c < NCHUNK) load_chunk(W, c, laneoff, cb);
    mac_chunk(ca, a00, a01, a11);
    if (c >= NCHUNK) break;
    c += GRAM_WAVES;
    if (c < NCHUNK) load_chunk(W, c, laneoff, ca);
    mac_chunk(cb, a00, a01, a11);
    if (c >= NCHUNK) break;
    c += GRAM_WAVES;
  }

  // ---------------- block reduce (4 waves -> 2 -> sliced atomics) ----------------
  if (wave < 2) {
#pragma unroll
    for (int rg = 0; rg < 16; ++rg) {
      red[wave][       rg * 64 + lane] = a00[rg];
      red[wave][1024 + rg * 64 + lane] = a01[rg];
      red[wave][2048 + rg * 64 + lane] = a11[rg];
    }
  }
  __syncthreads();
  if (wave >= 2) {
    float* dst = red[wave - 2];
#pragma unroll
    for (int rg = 0; rg < 16; ++rg) {
      dst[       rg * 64 + lane] += a00[rg];
      dst[1024 + rg * 64 + lane] += a01[rg];
      dst[2048 + rg * 64 + lane] += a11[rg];
    }
  }
  __syncthreads();
  float* slice = ws + 128 + (bid & (NSLICE - 1)) * 3072;
  for (int e = tid; e < 3072; e += BLOCK)
    atomicAdd(&slice[e], red[0][e] + red[1][e]);
}

__global__ __launch_bounds__(256) void k_fin(const float* __restrict__ ws,
                                             float* __restrict__ out) {
  __shared__ float g[3072];
  __shared__ float n2[64];
  __shared__ float wsum[4];
  __shared__ float msum_s[4];
  const int tid = threadIdx.x;
  const int wave = tid >> 6, lane = tid & 63;

  for (int e = tid; e < 3072; e += 256) {
    float s = 0.f;
#pragma unroll
    for (int sl = 0; sl < NSLICE; ++sl) s += ws[128 + sl * 3072 + e];
    g[e] = s;
  }
  // MSE total: 128 partials
  float m = (tid < 128) ? ws[tid] : 0.f;
#pragma unroll
  for (int o = 32; o; o >>= 1) m += __shfl_xor(m, o, 64);
  if (lane == 0) msum_s[wave] = m;
  __syncthreads();

  // C/D layout of 32x32 mfma: col = lane&31, row = (reg&3) + 8*(reg>>2) + 4*(lane>>5)
  for (int e = tid; e < 3072; e += 256) {
    int tl = e >> 10, rg = (e >> 6) & 15, l = e & 63;
    int il = (rg & 3) + 8 * (rg >> 2) + 4 * (l >> 5);
    int jl = l & 31;
    if (tl != 1 && il == jl) n2[il + (tl == 2 ? 32 : 0)] = g[e];
  }
  __syncthreads();

  float local = 0.f;
  for (int e = tid; e < 3072; e += 256) {
    int tl = e >> 10, rg = (e >> 6) & 15, l = e & 63;
    int il = (rg & 3) + 8 * (rg >> 2) + 4 * (l >> 5);
    int jl = l & 31;
    int i, j; float wgt;
    if (tl == 0)      { i = il;      j = jl;      wgt = 1.f; }
    else if (tl == 1) { i = il;      j = jl + 32; wgt = 2.f; }  // symmetric quadrant
    else              { i = il + 32; j = jl + 32; wgt = 1.f; }
    if (i != j) {
      float sim = g[e] / sqrtf(n2[i] * n2[j]);
      if (sim > 0.2f && sim <= 1.0f) local += wgt * sim;
    }
  }
#pragma unroll
  for (int o = 32; o; o >>= 1) local += __shfl_xor(local, o, 64);
  if (lane == 0) wsum[wave] = local;
  __syncthreads();
  if (tid == 0) {
    float reg_sum = wsum[0] + wsum[1] + wsum[2] + wsum[3];
    float mse_sum = msum_s[0] + msum_s[1] + msum_s[2] + msum_s[3];
    out[0] = mse_sum * (1.0f / 8388608.0f) + 0.0005f * reg_sum;
  }
}

extern "C" void kernel_launch(void* const* d_in, const int* in_sizes, int n_in,
                              void* d_out, int out_size, void* d_ws, size_t ws_size,
                              hipStream_t stream) {
  const float* X = (const float*)d_in[0];
  const float* Y = (const float*)d_in[1];
  const float* W = (const float*)d_in[2];
  float* ws = (float*)d_ws;

  // zero only the gram slice region (8*3072 floats at float-offset 128)
  hipMemsetAsync((void*)((char*)d_ws + 128 * sizeof(float)), 0,
                 NSLICE * 3072 * sizeof(float), stream);
  k_main<<<GRAM_BLOCKS + MSE_BLOCKS, BLOCK, 0, stream>>>(X, Y, W, ws);
  k_fin<<<1, 256, 0, stream>>>(ws, (float*)d_out);
}

// Round 4
// 61.634 us; speedup vs baseline: 1.0585x; 1.0585x over previous
//
#include <hip/hip_runtime.h>

typedef __attribute__((ext_vector_type(8)))  short   short8;
typedef __attribute__((ext_vector_type(4)))  unsigned uint4v;
typedef __attribute__((ext_vector_type(16))) float   f32x16;
typedef __attribute__((ext_vector_type(4)))  float   f4;

constexpr int GRAM_BLOCKS = 384;
constexpr int MSE_BLOCKS  = 128;
constexpr int BLOCK       = 256;          // 4 waves
constexpr int CHUNK_F     = 3072;         // 16 slabs x 192 floats
constexpr int NCHUNK      = 16384;
constexpr int GRAM_WAVES  = GRAM_BLOCKS * 4;    // 1536 (chunk grid-stride)
constexpr int MSE_THREADS = MSE_BLOCKS * BLOCK; // 32768 -> exactly 64 iters
constexpr int RED_BLOCKS  = 96;                 // node-B reduce blocks (32 entries each)

// ws float-offsets:
//   [0..128)    MSE per-block partials (plain stores)
//   [128..224)  96 int flags (self-resetting: set 1 w/ release, block0 resets to 0)
//   [256..3328) gram_final (3072)
//   [4096..4096+384*3072) per-block gram partials (plain stores)
constexpr int MSE_OFF  = 0;
constexpr int FLAG_OFF = 128;
constexpr int GF_OFF   = 256;
constexpr int PART_OFF = 4096;

struct F3 { float v[3]; };                 // 12B -> global_load_dwordx3
struct Chunk { F3 a0[4], a1[4], b0[4], b1[4]; };

// pack two f32 -> one u32 of 2 bf16 (round-half-up): 2 add + 1 v_perm
__device__ __forceinline__ unsigned pk_bf16(float a, float b) {
  unsigned a2 = __builtin_bit_cast(unsigned, a) + 0x8000u;
  unsigned b2 = __builtin_bit_cast(unsigned, b) + 0x8000u;
  return __builtin_amdgcn_perm(b2, a2, 0x07060302u);
}

__device__ __forceinline__ void load_chunk(const float* __restrict__ W, int c,
                                           int laneoff, Chunk& ch) {
  const float* s = W + (size_t)c * CHUNK_F + laneoff;
#pragma unroll
  for (int bp = 0; bp < 4; ++bp) {
    const float* p = s + bp * 384;     // slab pair (2bp, 2bp+1) of this half
    ch.a0[bp] = *(const F3*)(p);       // slab even, row r
    ch.a1[bp] = *(const F3*)(p + 96);  // slab even, row r+32
    ch.b0[bp] = *(const F3*)(p + 192); // slab odd,  row r
    ch.b1[bp] = *(const F3*)(p + 288); // slab odd,  row r+32
  }
}

__device__ __forceinline__ void mac_chunk(const Chunk& c, f32x16& a00, f32x16& a01,
                                          f32x16& a11) {
#pragma unroll
  for (int k = 0; k < 3; ++k) {
    unsigned fl[4], fh[4];
#pragma unroll
    for (int bp = 0; bp < 4; ++bp) {
      fl[bp] = pk_bf16(c.a0[bp].v[k], c.b0[bp].v[k]);
      fh[bp] = pk_bf16(c.a1[bp].v[k], c.b1[bp].v[k]);
    }
    uint4v vl = {fl[0], fl[1], fl[2], fl[3]};
    uint4v vh = {fh[0], fh[1], fh[2], fh[3]};
    short8 lo = __builtin_bit_cast(short8, vl);
    short8 hv = __builtin_bit_cast(short8, vh);
    a00 = __builtin_amdgcn_mfma_f32_32x32x16_bf16(lo, lo, a00, 0, 0, 0);
    a01 = __builtin_amdgcn_mfma_f32_32x32x16_bf16(lo, hv, a01, 0, 0, 0);
    a11 = __builtin_amdgcn_mfma_f32_32x32x16_bf16(hv, hv, a11, 0, 0, 0);
  }
}

__global__ __launch_bounds__(BLOCK, 2) void k_a(
    const float* __restrict__ X, const float* __restrict__ Y,
    const float* __restrict__ W, float* __restrict__ ws) {
  __shared__ __align__(16) float red[2][3072];   // 24 KiB
  const int bid = blockIdx.x;
  const int tid = threadIdx.x;
  const int wave = tid >> 6;
  const int lane = tid & 63;

  if (bid >= GRAM_BLOCKS) {
    // ---------------- MSE partial: nontemporal reads (keep W cache-resident) ----
    const unsigned t0 = (unsigned)((bid - GRAM_BLOCKS) * BLOCK + tid);
    const f4* x4 = (const f4*)X;
    const f4* y4 = (const f4*)Y;
    float acc = 0.f;
#pragma unroll 8
    for (int it = 0; it < 64; ++it) {
      unsigned i = t0 + (unsigned)it * (unsigned)MSE_THREADS;
      f4 a = __builtin_nontemporal_load(x4 + i);
      f4 b = __builtin_nontemporal_load(y4 + i);
      float d0 = a[0] - b[0], d1 = a[1] - b[1], d2 = a[2] - b[2], d3 = a[3] - b[3];
      acc += d0 * d0 + d1 * d1 + d2 * d2 + d3 * d3;
    }
#pragma unroll
    for (int o = 32; o; o >>= 1) acc += __shfl_xor(acc, o, 64);
    __shared__ float wsum[4];
    if (lane == 0) wsum[wave] = acc;
    __syncthreads();
    if (tid == 0) ws[MSE_OFF + bid - GRAM_BLOCKS] = wsum[0] + wsum[1] + wsum[2] + wsum[3];
    return;
  }

  // ------------- Gram partial: grid-stride chunks, reg double-buffer -------------
  const int r    = lane & 31;
  const int hi   = lane >> 5;
  const int laneoff = hi * 1536 + 3 * r;   // (hi*8 slabs)*192 + row r
  const int wg = bid * 4 + wave;           // 0..1535

  f32x16 a00{}, a01{}, a11{};
  Chunk ca, cb;
  int c = wg;
  load_chunk(W, c, laneoff, ca);
  c += GRAM_WAVES;
  for (;;) {
    if (c < NCHUNK) load_chunk(W, c, laneoff, cb);
    mac_chunk(ca, a00, a01, a11);
    if (c >= NCHUNK) break;
    c += GRAM_WAVES;
    if (c < NCHUNK) load_chunk(W, c, laneoff, ca);
    mac_chunk(cb, a00, a01, a11);
    if (c >= NCHUNK) break;
    c += GRAM_WAVES;
  }

  // -------- block reduce (4 waves -> 2 -> plain coalesced partial store) --------
  if (wave < 2) {
#pragma unroll
    for (int rg = 0; rg < 16; ++rg) {
      red[wave][       rg * 64 + lane] = a00[rg];
      red[wave][1024 + rg * 64 + lane] = a01[rg];
      red[wave][2048 + rg * 64 + lane] = a11[rg];
    }
  }
  __syncthreads();
  if (wave >= 2) {
    float* dst = red[wave - 2];
#pragma unroll
    for (int rg = 0; rg < 16; ++rg) {
      dst[       rg * 64 + lane] += a00[rg];
      dst[1024 + rg * 64 + lane] += a01[rg];
      dst[2048 + rg * 64 + lane] += a11[rg];
    }
  }
  __syncthreads();
  const f4* r0 = (const f4*)&red[0][0];
  const f4* r1 = (const f4*)&red[1][0];
  f4* p4 = (f4*)(ws + PART_OFF + (size_t)bid * 3072);
#pragma unroll
  for (int q = tid; q < 768; q += BLOCK) {
    f4 a = r0[q], b = r1[q];
    p4[q] = a + b;
  }
}

__global__ __launch_bounds__(256) void k_b(float* __restrict__ ws,
                                           float* __restrict__ out) {
  __shared__ float r2[4][32];
  __shared__ float g[3072];
  __shared__ float n2[64];
  __shared__ float msum_s[4];
  __shared__ float wsum[4];
  const int tid = threadIdx.x;
  const int lane = tid & 63, wv = tid >> 6, el = lane & 31, ph = lane >> 5;
  const int b = blockIdx.x;
  const int w0 = b * 32;
  int* flags = (int*)(ws + FLAG_OFF);

  // ---- reduce 384 partials over this block's 32-entry window ----
  const float* base = ws + PART_OFF + (size_t)(ph + 2 * wv) * 3072 + w0 + el;
  float acc = 0.f;
#pragma unroll 8
  for (int i = 0; i < 48; ++i) acc += base[(size_t)i * 24576];
  acc += __shfl_xor(acc, 32, 64);
  if (ph == 0) r2[wv][el] = acc;
  __syncthreads();
  if (tid < 32)
    ws[GF_OFF + w0 + tid] = r2[0][tid] + r2[1][tid] + r2[2][tid] + r2[3][tid];
  __syncthreads();   // drains wave-0's stores (vmcnt) before publishing
  if (tid == 0) {
    __threadfence(); // write-back L2 so other-XCD reader sees gram_final
    __hip_atomic_store(&flags[b], 1, __ATOMIC_RELEASE, __HIP_MEMORY_SCOPE_AGENT);
  }
  if (b != 0) return;

  // ---- block 0: wait for all 96 windows, then finalize ----
  if (tid < RED_BLOCKS) {
    while (__hip_atomic_load(&flags[tid], __ATOMIC_RELAXED,
                             __HIP_MEMORY_SCOPE_AGENT) != 1)
      __builtin_amdgcn_s_sleep(8);
  }
  __syncthreads();
  __threadfence();   // acquire side: invalidate local caches before data reads

  for (int e = tid; e < 3072; e += 256) g[e] = ws[GF_OFF + e];

  float m = (tid < 128) ? ws[MSE_OFF + tid] : 0.f;
#pragma unroll
  for (int o = 32; o; o >>= 1) m += __shfl_xor(m, o, 64);
  if (lane == 0) msum_s[wv] = m;
  __syncthreads();

  // reset flags for the next replay (graph-capture safe, deterministic)
  if (tid < RED_BLOCKS) flags[tid] = 0;

  // C/D layout of 32x32 mfma: col = lane&31, row = (reg&3) + 8*(reg>>2) + 4*(lane>>5)
  for (int e = tid; e < 3072; e += 256) {
    int tl = e >> 10, rg = (e >> 6) & 15, l = e & 63;
    int il = (rg & 3) + 8 * (rg >> 2) + 4 * (l >> 5);
    int jl = l & 31;
    if (tl != 1 && il == jl) n2[il + (tl == 2 ? 32 : 0)] = g[e];
  }
  __syncthreads();

  float local = 0.f;
  for (int e = tid; e < 3072; e += 256) {
    int tl = e >> 10, rg = (e >> 6) & 15, l = e & 63;
    int il = (rg & 3) + 8 * (rg >> 2) + 4 * (l >> 5);
    int jl = l & 31;
    int i, j; float wgt;
    if (tl == 0)      { i = il;      j = jl;      wgt = 1.f; }
    else if (tl == 1) { i = il;      j = jl + 32; wgt = 2.f; }  // symmetric quadrant
    else              { i = il + 32; j = jl + 32; wgt = 1.f; }
    if (i != j) {
      float sim = g[e] / sqrtf(n2[i] * n2[j]);
      if (sim > 0.2f && sim <= 1.0f) local += wgt * sim;
    }
  }
#pragma unroll
  for (int o = 32; o; o >>= 1) local += __shfl_xor(local, o, 64);
  if (lane == 0) wsum[wv] = local;
  __syncthreads();
  if (tid == 0) {
    float reg_sum = wsum[0] + wsum[1] + wsum[2] + wsum[3];
    float mse_sum = msum_s[0] + msum_s[1] + msum_s[2] + msum_s[3];
    out[0] = mse_sum * (1.0f / 8388608.0f) + 0.0005f * reg_sum;
  }
}

extern "C" void kernel_launch(void* const* d_in, const int* in_sizes, int n_in,
                              void* d_out, int out_size, void* d_ws, size_t ws_size,
                              hipStream_t stream) {
  const float* X = (const float*)d_in[0];
  const float* Y = (const float*)d_in[1];
  const float* W = (const float*)d_in[2];
  float* ws = (float*)d_ws;

  k_a<<<GRAM_BLOCKS + MSE_BLOCKS, BLOCK, 0, stream>>>(X, Y, W, ws);
  k_b<<<RED_BLOCKS, 256, 0, stream>>>(ws, (float*)d_out);
}